// Round 1
// baseline (407.376 us; speedup 1.0000x reference)
//
#include <hip/hip_runtime.h>

// AutoInt fused kernel: embedding gather -> 2x MHSA over 32 fields -> logit.
// One block (256 thr, 4 waves) per sample; wave h handles head h.
// All matmuls via mfma_f32_16x16x32_bf16. Weights pre-converted to bf16 in ws.

#define NSAMP 8192
#define S_Y 136   // y row stride (bf16 elems), 16B-aligned rows, breaks pow2 banks
#define S_T 56    // per-head tile stride (bf16 elems), 112B rows
#define S_S 33    // fp32 score stride

typedef __attribute__((ext_vector_type(8))) short bf8_t;  // 8 bf16
typedef __attribute__((ext_vector_type(4))) float f4_t;   // 4 fp32 acc

__device__ __forceinline__ short f2bf(float f) {
  unsigned u = __float_as_uint(f);
  u += 0x7fffu + ((u >> 16) & 1u);   // RNE
  return (short)(u >> 16);
}
__device__ __forceinline__ float bf2f(short s) {
  return __uint_as_float(((unsigned)(unsigned short)s) << 16);
}
__device__ __forceinline__ f4_t mfma16(bf8_t a, bf8_t b, f4_t c) {
  return __builtin_amdgcn_mfma_f32_16x16x32_bf16(a, b, c, 0, 0, 0);
}

// out[f][n0+n] = sum_d y[f][d] * W[n0+n][d] + bias[n0+n]; 32x32 tile as 2x2 MFMA tiles
template<int D_IN>
__device__ __forceinline__ void proj(const bf8_t (&af)[2][D_IN / 32],
                                     const short* __restrict__ W,
                                     const float* __restrict__ bias,
                                     int n0, int c, int quad, f4_t (&acc)[2][2]) {
  constexpr int KS = D_IN / 32;
#pragma unroll
  for (int ni = 0; ni < 2; ++ni) {
    float bb = bias[n0 + ni * 16 + c];
    bf8_t bfr[KS];
#pragma unroll
    for (int k = 0; k < KS; ++k)
      bfr[k] = *(const bf8_t*)&W[(n0 + ni * 16 + c) * D_IN + k * 32 + quad * 8];
#pragma unroll
    for (int mi = 0; mi < 2; ++mi) {
      f4_t a; a[0] = bb; a[1] = bb; a[2] = bb; a[3] = bb;
#pragma unroll
      for (int k = 0; k < KS; ++k) a = mfma16(af[mi][k], bfr[k], a);
      acc[mi][ni] = a;
    }
  }
}

template<int D_IN>
__device__ void attn_layer(const short* yIn, short* yOut,
                           const short* __restrict__ Wq, const short* __restrict__ Wk,
                           const short* __restrict__ Wv, const short* __restrict__ Wr,
                           const float* __restrict__ bq, const float* __restrict__ bk,
                           const float* __restrict__ bvp, const float* __restrict__ br,
                           short* bQ, short* bK, short* bV, float* bS) {
  constexpr int KS = D_IN / 32;
  const int lane = threadIdx.x & 63;
  const int c = lane & 15;
  const int quad = lane >> 4;
  const int head = threadIdx.x >> 6;
  const int n0 = head * 32;

  // A fragments of yIn (shared by Q/K/V/R projections)
  bf8_t af[2][KS];
#pragma unroll
  for (int mi = 0; mi < 2; ++mi)
#pragma unroll
    for (int k = 0; k < KS; ++k)
      af[mi][k] = *(const bf8_t*)&yIn[(mi * 16 + c) * S_Y + k * 32 + quad * 8];

  f4_t acc[2][2];

  // ---- Q -> LDS row-major bf16
  proj<D_IN>(af, Wq, bq, n0, c, quad, acc);
#pragma unroll
  for (int mi = 0; mi < 2; ++mi)
#pragma unroll
    for (int ni = 0; ni < 2; ++ni)
#pragma unroll
      for (int r = 0; r < 4; ++r)
        bQ[(mi * 16 + quad * 4 + r) * S_T + ni * 16 + c] = f2bf(acc[mi][ni][r]);

  // ---- K -> LDS row-major bf16
  proj<D_IN>(af, Wk, bk, n0, c, quad, acc);
#pragma unroll
  for (int mi = 0; mi < 2; ++mi)
#pragma unroll
    for (int ni = 0; ni < 2; ++ni)
#pragma unroll
      for (int r = 0; r < 4; ++r)
        bK[(mi * 16 + quad * 4 + r) * S_T + ni * 16 + c] = f2bf(acc[mi][ni][r]);

  // ---- Res -> registers (C-layout matches O's C-layout)
  f4_t res[2][2];
  proj<D_IN>(af, Wr, br, n0, c, quad, res);

  // ---- scores = Q K^T (K=32, one MFMA per tile) -> fp32 LDS
#pragma unroll
  for (int mi = 0; mi < 2; ++mi) {
    bf8_t qa = *(const bf8_t*)&bQ[(mi * 16 + c) * S_T + quad * 8];
#pragma unroll
    for (int ni = 0; ni < 2; ++ni) {
      bf8_t kb = *(const bf8_t*)&bK[(ni * 16 + c) * S_T + quad * 8];
      f4_t z; z[0] = 0.f; z[1] = 0.f; z[2] = 0.f; z[3] = 0.f;
      z = mfma16(qa, kb, z);
#pragma unroll
      for (int r = 0; r < 4; ++r)
        bS[(mi * 16 + quad * 4 + r) * S_S + ni * 16 + c] = z[r];
    }
  }

  // ---- softmax over rows (2 lanes per row, 16 cols each), A -> bQ (bf16)
  {
    int r = lane >> 1, hf = lane & 1;
    const float* srow = &bS[r * S_S + hf * 16];
    float mx = srow[0];
#pragma unroll
    for (int j = 1; j < 16; ++j) mx = fmaxf(mx, srow[j]);
    mx = fmaxf(mx, __shfl_xor(mx, 1));
    float e[16]; float sum = 0.f;
#pragma unroll
    for (int j = 0; j < 16; ++j) { e[j] = __expf(srow[j] - mx); sum += e[j]; }
    sum += __shfl_xor(sum, 1);
    float inv = 1.f / sum;
#pragma unroll
    for (int j = 0; j < 16; ++j) bQ[r * S_T + hf * 16 + j] = f2bf(e[j] * inv);
  }

  // ---- V -> LDS transposed bV[i][k] = V[k][i]  (overlays bS; same-wave DS is in-order)
  proj<D_IN>(af, Wv, bvp, n0, c, quad, acc);
#pragma unroll
  for (int mi = 0; mi < 2; ++mi)
#pragma unroll
    for (int ni = 0; ni < 2; ++ni) {
      short4 pk;
      pk.x = f2bf(acc[mi][ni][0]); pk.y = f2bf(acc[mi][ni][1]);
      pk.z = f2bf(acc[mi][ni][2]); pk.w = f2bf(acc[mi][ni][3]);
      *(short4*)&bV[(ni * 16 + c) * S_T + mi * 16 + quad * 4] = pk;
    }

  // ---- O = A V + Res, relu -> yOut (bf16, this head's 32 cols)
#pragma unroll
  for (int mi = 0; mi < 2; ++mi) {
    bf8_t pa = *(const bf8_t*)&bQ[(mi * 16 + c) * S_T + quad * 8];
#pragma unroll
    for (int ni = 0; ni < 2; ++ni) {
      bf8_t vb = *(const bf8_t*)&bV[(ni * 16 + c) * S_T + quad * 8];
      f4_t o = mfma16(pa, vb, res[mi][ni]);
#pragma unroll
      for (int r = 0; r < 4; ++r)
        yOut[(mi * 16 + quad * 4 + r) * S_Y + n0 + ni * 16 + c] =
            f2bf(fmaxf(o[r], 0.f));
    }
  }
}

__global__ __launch_bounds__(256, 2) void autoint_main(
    const int* __restrict__ onehot_i, const float* __restrict__ onehot_x,
    const int* __restrict__ mh_i, const float* __restrict__ mh_x,
    const float* __restrict__ ctns, const float* __restrict__ xx,
    const float* __restrict__ xy,
    const float* __restrict__ bq1, const float* __restrict__ bk1,
    const float* __restrict__ bv1, const float* __restrict__ br1,
    const float* __restrict__ bq2, const float* __restrict__ bk2,
    const float* __restrict__ bv2, const float* __restrict__ br2,
    const float* __restrict__ logitb, const short* __restrict__ wbf,
    float* __restrict__ out) {
  __shared__ short yA[32 * S_Y];          // 8704 B
  __shared__ short yB[32 * S_Y];          // 8704 B
  __shared__ char scratch[4][11392];      // per-wave: Q(3584) K(3584) V/S(4224)
  __shared__ float red[4];

  const int s = blockIdx.x;
  const int t = threadIdx.x;
  const int head = t >> 6;

  short* bQ = (short*)&scratch[head][0];
  short* bK = (short*)&scratch[head][3584];
  short* bV = (short*)&scratch[head][7168];
  float* bS = (float*)&scratch[head][7168];

  // ---- embedding build into yA [32][64]
  for (int idx = t; idx < 1280; idx += 256) {   // 20 onehot fields x 64
    int f = idx >> 6, e = idx & 63;
    int row = onehot_i[s * 20 + f];
    yA[f * S_Y + e] = f2bf(xx[row * 64 + e] * onehot_x[s * 20 + f]);
  }
  if (t < 128) {                                 // 2 multihot fields x 64
    int j = t >> 6, e = t & 63;
    const int* ip = &mh_i[(j * NSAMP + s) * 50];
    const float* xp = &mh_x[(j * NSAMP + s) * 50];
    float a = 0.f;
    for (int k2 = 0; k2 < 50; ++k2) a += xx[ip[k2] * 64 + e] * xp[k2];
    yA[(20 + j) * S_Y + e] = f2bf(a);
  }
  for (int idx = t; idx < 640; idx += 256) {     // 10 ctns fields x 64
    int ci = idx >> 6, e = idx & 63;
    yA[(22 + ci) * S_Y + e] = f2bf(ctns[s * 10 + ci] * xy[ci * 64 + e]);
  }
  __syncthreads();

  attn_layer<64>(yA, yB, wbf + 0, wbf + 8192, wbf + 16384, wbf + 24576,
                 bq1, bk1, bv1, br1, bQ, bK, bV, bS);
  __syncthreads();
  attn_layer<128>(yB, yA, wbf + 32768, wbf + 49152, wbf + 65536, wbf + 81920,
                  bq2, bk2, bv2, br2, bQ, bK, bV, bS);
  __syncthreads();

  // ---- logit: dot(flat[4096], logitW) + b -> sigmoid
  const short* lw = wbf + 98304;
  float p = 0.f;
#pragma unroll
  for (int i = 0; i < 16; ++i) {
    int idx = t + 256 * i;
    p += bf2f(yA[(idx >> 7) * S_Y + (idx & 127)]) * bf2f(lw[idx]);
  }
#pragma unroll
  for (int o = 32; o > 0; o >>= 1) p += __shfl_xor(p, o);
  if ((t & 63) == 0) red[head] = p;
  __syncthreads();
  if (t == 0) {
    float z = red[0] + red[1] + red[2] + red[3] + logitb[0];
    out[s] = 1.f / (1.f + __expf(-z));
  }
}

// fp32 -> bf16 weight conversion into ws:
// [0)QW1 [8192)KW1 [16384)VW1 [24576)RW1 [32768)QW2 [49152)KW2 [65536)VW2 [81920)RW2 [98304)logitW(4096)
__global__ void convert_w(const float* __restrict__ qw1, const float* __restrict__ kw1,
                          const float* __restrict__ vw1, const float* __restrict__ rw1,
                          const float* __restrict__ qw2, const float* __restrict__ kw2,
                          const float* __restrict__ vw2, const float* __restrict__ rw2,
                          const float* __restrict__ lw, short* __restrict__ outw) {
  int i = blockIdx.x * 256 + threadIdx.x;
  if (i >= 102400) return;
  float v;
  if (i < 32768) {
    int tsel = i >> 13, j = i & 8191;
    const float* src = tsel == 0 ? qw1 : tsel == 1 ? kw1 : tsel == 2 ? vw1 : rw1;
    v = src[j];
  } else if (i < 98304) {
    int k = i - 32768;
    int tsel = k >> 14, j = k & 16383;
    const float* src = tsel == 0 ? qw2 : tsel == 1 ? kw2 : tsel == 2 ? vw2 : rw2;
    v = src[j];
  } else {
    v = lw[i - 98304];
  }
  outw[i] = f2bf(v);
}

extern "C" void kernel_launch(void* const* d_in, const int* in_sizes, int n_in,
                              void* d_out, int out_size, void* d_ws, size_t ws_size,
                              hipStream_t stream) {
  short* wbf = (short*)d_ws;  // 204800 bytes used
  convert_w<<<400, 256, 0, stream>>>(
      (const float*)d_in[7], (const float*)d_in[9], (const float*)d_in[11],
      (const float*)d_in[13], (const float*)d_in[15], (const float*)d_in[17],
      (const float*)d_in[19], (const float*)d_in[21], (const float*)d_in[23], wbf);
  autoint_main<<<NSAMP, 256, 0, stream>>>(
      (const int*)d_in[0], (const float*)d_in[1], (const int*)d_in[2],
      (const float*)d_in[3], (const float*)d_in[4], (const float*)d_in[5],
      (const float*)d_in[6],
      (const float*)d_in[8], (const float*)d_in[10], (const float*)d_in[12],
      (const float*)d_in[14], (const float*)d_in[16], (const float*)d_in[18],
      (const float*)d_in[20], (const float*)d_in[22], (const float*)d_in[24],
      wbf, (float*)d_out);
}

// Round 2
// 388.792 us; speedup vs baseline: 1.0478x; 1.0478x over previous
//
#include <hip/hip_runtime.h>

// AutoInt fused: embedding gather -> 2x MHSA (32 fields, 4 heads x 32) -> logit.
// One block (256 thr, 4 waves) per sample; wave h = head h.
// R2: LDS 63.5KB -> 33.8KB (4 blocks/CU), register-shuffle softmax,
//     logit fused into layer-2 epilogue, Q/P and K/V buffer overlays.

#define NSAMP 8192
#define S_Y1 72    // layer1 input stride (shorts): 144B rows, 16B-aligned
#define S_Y2 136   // layer2 input stride (shorts): 272B rows
#define S_T 40     // per-head 32x32 tile stride (shorts): 80B rows

typedef __attribute__((ext_vector_type(8))) short bf8_t;  // 8 bf16
typedef __attribute__((ext_vector_type(4))) float f4_t;   // 4 fp32

__device__ __forceinline__ short f2bf(float f) {
  unsigned u = __float_as_uint(f);
  u += 0x7fffu + ((u >> 16) & 1u);   // RNE
  return (short)(u >> 16);
}
__device__ __forceinline__ unsigned pack2(float a, float b) {
  return ((unsigned)(unsigned short)f2bf(a)) |
         (((unsigned)(unsigned short)f2bf(b)) << 16);
}
__device__ __forceinline__ float bf2f(short s) {
  return __uint_as_float(((unsigned)(unsigned short)s) << 16);
}
__device__ __forceinline__ f4_t mfma16(bf8_t a, bf8_t b, f4_t c) {
  return __builtin_amdgcn_mfma_f32_16x16x32_bf16(a, b, c, 0, 0, 0);
}

// acc[mi][ni] C-tile of: out[f][n0+n] = sum_d y[f][d]*W[n0+n][d] + b[n0+n]
template<int D_IN>
__device__ __forceinline__ void proj(const bf8_t (&af)[2][D_IN / 32],
                                     const short* __restrict__ W,
                                     const float* __restrict__ bias,
                                     int n0, int c, int quad, f4_t (&acc)[2][2]) {
  constexpr int KS = D_IN / 32;
#pragma unroll
  for (int ni = 0; ni < 2; ++ni) {
    float bb = bias[n0 + ni * 16 + c];
    bf8_t bfr[KS];
#pragma unroll
    for (int k = 0; k < KS; ++k)
      bfr[k] = *(const bf8_t*)&W[(n0 + ni * 16 + c) * D_IN + k * 32 + quad * 8];
#pragma unroll
    for (int mi = 0; mi < 2; ++mi) {
      f4_t a; a[0] = bb; a[1] = bb; a[2] = bb; a[3] = bb;
#pragma unroll
      for (int k = 0; k < KS; ++k) a = mfma16(af[mi][k], bfr[k], a);
      acc[mi][ni] = a;
    }
  }
}

// One attention layer for this wave's head. bQ/bK are per-wave 32xS_T tiles.
// FUSE: instead of storing yOut, dot relu(O+Res) with lw and return partial.
template<int D_IN, int S_IN, bool FUSE>
__device__ float attn_layer(const short* yIn, short* yOut,
                            const short* __restrict__ Wq, const short* __restrict__ Wk,
                            const short* __restrict__ Wv, const short* __restrict__ Wr,
                            const float* __restrict__ bq, const float* __restrict__ bk,
                            const float* __restrict__ bvp, const float* __restrict__ br,
                            short* bQ, short* bK, const short* __restrict__ lwg) {
  constexpr int KS = D_IN / 32;
  const int lane = threadIdx.x & 63;
  const int c = lane & 15;
  const int quad = lane >> 4;
  const int head = threadIdx.x >> 6;
  const int n0 = head * 32;

  // A-fragments of yIn (shared across Q/K/V/R projections)
  bf8_t af[2][KS];
#pragma unroll
  for (int mi = 0; mi < 2; ++mi)
#pragma unroll
    for (int k = 0; k < KS; ++k)
      af[mi][k] = *(const bf8_t*)&yIn[(mi * 16 + c) * S_IN + k * 32 + quad * 8];

  f4_t acc[2][2];

  // ---- Q -> bQ (row-major bf16)
  proj<D_IN>(af, Wq, bq, n0, c, quad, acc);
#pragma unroll
  for (int mi = 0; mi < 2; ++mi)
#pragma unroll
    for (int ni = 0; ni < 2; ++ni)
#pragma unroll
      for (int r = 0; r < 4; ++r)
        bQ[(mi * 16 + quad * 4 + r) * S_T + ni * 16 + c] = f2bf(acc[mi][ni][r]);

  // ---- K -> bK (row-major bf16)
  proj<D_IN>(af, Wk, bk, n0, c, quad, acc);
#pragma unroll
  for (int mi = 0; mi < 2; ++mi)
#pragma unroll
    for (int ni = 0; ni < 2; ++ni)
#pragma unroll
      for (int r = 0; r < 4; ++r)
        bK[(mi * 16 + quad * 4 + r) * S_T + ni * 16 + c] = f2bf(acc[mi][ni][r]);

  // ---- Res -> registers (C-layout, same as O's)
  f4_t res[2][2];
  proj<D_IN>(af, Wr, br, n0, c, quad, res);

  // ---- scores = Q K^T, kept in registers (C-layout)
  f4_t z[2][2];
#pragma unroll
  for (int mi = 0; mi < 2; ++mi) {
    bf8_t qa = *(const bf8_t*)&bQ[(mi * 16 + c) * S_T + quad * 8];
#pragma unroll
    for (int ni = 0; ni < 2; ++ni) {
      bf8_t kb = *(const bf8_t*)&bK[(ni * 16 + c) * S_T + quad * 8];
      f4_t zz; zz[0] = 0.f; zz[1] = 0.f; zz[2] = 0.f; zz[3] = 0.f;
      z[mi][ni] = mfma16(qa, kb, zz);
    }
  }

  // ---- register softmax: row (mi*16+quad*4+r) spans ni x 16 c-lanes
  float inv[2][4];
#pragma unroll
  for (int mi = 0; mi < 2; ++mi)
#pragma unroll
    for (int r = 0; r < 4; ++r) {
      float m = fmaxf(z[mi][0][r], z[mi][1][r]);
      m = fmaxf(m, __shfl_xor(m, 1));
      m = fmaxf(m, __shfl_xor(m, 2));
      m = fmaxf(m, __shfl_xor(m, 4));
      m = fmaxf(m, __shfl_xor(m, 8));
      float e0 = __expf(z[mi][0][r] - m);
      float e1 = __expf(z[mi][1][r] - m);
      z[mi][0][r] = e0; z[mi][1][r] = e1;
      float s = e0 + e1;
      s += __shfl_xor(s, 1);
      s += __shfl_xor(s, 2);
      s += __shfl_xor(s, 4);
      s += __shfl_xor(s, 8);
      inv[mi][r] = 1.f / s;
    }

  // ---- P -> bQ (overwrites dead Q; same-wave DS ops are in-order)
#pragma unroll
  for (int mi = 0; mi < 2; ++mi)
#pragma unroll
    for (int ni = 0; ni < 2; ++ni)
#pragma unroll
      for (int r = 0; r < 4; ++r)
        bQ[(mi * 16 + quad * 4 + r) * S_T + ni * 16 + c] =
            f2bf(z[mi][ni][r] * inv[mi][r]);

  // ---- V -> bK transposed (overwrites dead K): bK[i][f] = V[f][i]
  proj<D_IN>(af, Wv, bvp, n0, c, quad, acc);
#pragma unroll
  for (int mi = 0; mi < 2; ++mi)
#pragma unroll
    for (int ni = 0; ni < 2; ++ni) {
      short4 pk;
      pk.x = f2bf(acc[mi][ni][0]); pk.y = f2bf(acc[mi][ni][1]);
      pk.z = f2bf(acc[mi][ni][2]); pk.w = f2bf(acc[mi][ni][3]);
      *(short4*)&bK[(ni * 16 + c) * S_T + mi * 16 + quad * 4] = pk;
    }

  // ---- O = P V + Res, relu; store (layer1) or fuse logit dot (layer2)
  float p = 0.f;
#pragma unroll
  for (int mi = 0; mi < 2; ++mi) {
    bf8_t pa = *(const bf8_t*)&bQ[(mi * 16 + c) * S_T + quad * 8];
#pragma unroll
    for (int ni = 0; ni < 2; ++ni) {
      bf8_t vb = *(const bf8_t*)&bK[(ni * 16 + c) * S_T + quad * 8];
      f4_t o = mfma16(pa, vb, res[mi][ni]);
#pragma unroll
      for (int r = 0; r < 4; ++r) {
        float ov = fmaxf(o[r], 0.f);
        int row = mi * 16 + quad * 4 + r;
        int col = n0 + ni * 16 + c;
        if (FUSE) {
          p += ov * bf2f(lwg[row * 128 + col]);
        } else {
          yOut[row * S_Y2 + col] = f2bf(ov);
        }
      }
    }
  }
  return p;
}

__global__ __launch_bounds__(256, 4) void autoint_main(
    const int* __restrict__ onehot_i, const float* __restrict__ onehot_x,
    const int* __restrict__ mh_i, const float* __restrict__ mh_x,
    const float* __restrict__ ctns, const float* __restrict__ xx,
    const float* __restrict__ xy,
    const float* __restrict__ bq1, const float* __restrict__ bk1,
    const float* __restrict__ bv1, const float* __restrict__ br1,
    const float* __restrict__ bq2, const float* __restrict__ bk2,
    const float* __restrict__ bv2, const float* __restrict__ br2,
    const float* __restrict__ logitb, const short* __restrict__ wbf,
    float* __restrict__ out) {
  __shared__ __align__(16) short yA[32 * S_Y1];      // 4608 B (layer1 in)
  __shared__ __align__(16) short yB[32 * S_Y2];      // 8704 B (layer1 out)
  __shared__ __align__(16) short scr[4][2][32 * S_T]; // 20480 B (Q/P, K/V per wave)
  __shared__ float red[4];

  const int s = blockIdx.x;
  const int t = threadIdx.x;
  const int head = t >> 6;
  short* bQ = scr[head][0];
  short* bK = scr[head][1];

  // ---- embedding build into yA [32][64] (bf16, packed-pair writes)
  for (int idx = t; idx < 640; idx += 256) {     // 20 onehot x 32 pairs
    int f = idx >> 5, ep = idx & 31;
    int row = onehot_i[s * 20 + f];
    float xw = onehot_x[s * 20 + f];
    float2 xv = *(const float2*)&xx[row * 64 + ep * 2];
    *(unsigned*)&yA[f * S_Y1 + ep * 2] = pack2(xv.x * xw, xv.y * xw);
  }
  {                                               // 2 multihot x 32 pairs, k split 4-way
    int slot = t >> 2, ks = t & 3;
    int j = slot >> 5, ep = slot & 31;
    const int* ip = &mh_i[(j * NSAMP + s) * 50];
    const float* xp = &mh_x[(j * NSAMP + s) * 50];
    float a0 = 0.f, a1 = 0.f;
    for (int k = ks; k < 50; k += 4) {
      float2 xv = *(const float2*)&xx[ip[k] * 64 + ep * 2];
      float w = xp[k];
      a0 += xv.x * w; a1 += xv.y * w;
    }
    a0 += __shfl_xor(a0, 1); a0 += __shfl_xor(a0, 2);
    a1 += __shfl_xor(a1, 1); a1 += __shfl_xor(a1, 2);
    if (ks == 0)
      *(unsigned*)&yA[(20 + j) * S_Y1 + ep * 2] = pack2(a0, a1);
  }
  for (int idx = t; idx < 320; idx += 256) {     // 10 ctns x 32 pairs
    int ci = idx >> 5, ep = idx & 31;
    float cv = ctns[s * 10 + ci];
    float2 xv = *(const float2*)&xy[ci * 64 + ep * 2];
    *(unsigned*)&yA[(22 + ci) * S_Y1 + ep * 2] = pack2(cv * xv.x, cv * xv.y);
  }
  __syncthreads();

  attn_layer<64, S_Y1, false>(yA, yB,
      wbf + 0, wbf + 8192, wbf + 16384, wbf + 24576,
      bq1, bk1, bv1, br1, bQ, bK, nullptr);
  __syncthreads();
  float p = attn_layer<128, S_Y2, true>(yB, nullptr,
      wbf + 32768, wbf + 49152, wbf + 65536, wbf + 81920,
      bq2, bk2, bv2, br2, bQ, bK, wbf + 98304);

  // ---- block reduce of logit partials, sigmoid
#pragma unroll
  for (int o = 32; o > 0; o >>= 1) p += __shfl_xor(p, o);
  if ((t & 63) == 0) red[head] = p;
  __syncthreads();
  if (t == 0) {
    float zz = red[0] + red[1] + red[2] + red[3] + logitb[0];
    out[s] = 1.f / (1.f + __expf(-zz));
  }
}

// fp32 -> bf16 weight conversion into ws:
// [0)QW1 [8192)KW1 [16384)VW1 [24576)RW1 [32768)QW2 [49152)KW2 [65536)VW2 [81920)RW2 [98304)logitW(4096)
__global__ void convert_w(const float* __restrict__ qw1, const float* __restrict__ kw1,
                          const float* __restrict__ vw1, const float* __restrict__ rw1,
                          const float* __restrict__ qw2, const float* __restrict__ kw2,
                          const float* __restrict__ vw2, const float* __restrict__ rw2,
                          const float* __restrict__ lw, short* __restrict__ outw) {
  int i = blockIdx.x * 256 + threadIdx.x;
  if (i >= 102400) return;
  float v;
  if (i < 32768) {
    int tsel = i >> 13, j = i & 8191;
    const float* src = tsel == 0 ? qw1 : tsel == 1 ? kw1 : tsel == 2 ? vw1 : rw1;
    v = src[j];
  } else if (i < 98304) {
    int k = i - 32768;
    int tsel = k >> 14, j = k & 16383;
    const float* src = tsel == 0 ? qw2 : tsel == 1 ? kw2 : tsel == 2 ? vw2 : rw2;
    v = src[j];
  } else {
    v = lw[i - 98304];
  }
  outw[i] = f2bf(v);
}

extern "C" void kernel_launch(void* const* d_in, const int* in_sizes, int n_in,
                              void* d_out, int out_size, void* d_ws, size_t ws_size,
                              hipStream_t stream) {
  short* wbf = (short*)d_ws;  // 204800 bytes used
  convert_w<<<400, 256, 0, stream>>>(
      (const float*)d_in[7], (const float*)d_in[9], (const float*)d_in[11],
      (const float*)d_in[13], (const float*)d_in[15], (const float*)d_in[17],
      (const float*)d_in[19], (const float*)d_in[21], (const float*)d_in[23], wbf);
  autoint_main<<<NSAMP, 256, 0, stream>>>(
      (const int*)d_in[0], (const float*)d_in[1], (const int*)d_in[2],
      (const float*)d_in[3], (const float*)d_in[4], (const float*)d_in[5],
      (const float*)d_in[6],
      (const float*)d_in[8], (const float*)d_in[10], (const float*)d_in[12],
      (const float*)d_in[14], (const float*)d_in[16], (const float*)d_in[18],
      (const float*)d_in[20], (const float*)d_in[22], (const float*)d_in[24],
      wbf, (float*)d_out);
}